// Round 5
// baseline (111.150 us; speedup 1.0000x reference)
//
#include <hip/hip_runtime.h>
#include <math.h>

#define B 32
#define N 16384
#define DIM 64
#define HID 64
#define KD 16
#define DM 512
#define MP 16

typedef __attribute__((ext_vector_type(8))) short bf16x8;
typedef __attribute__((ext_vector_type(4))) float f32x4;

__device__ __forceinline__ float fast_tanh(float a) {
  float e = __expf(2.f * a);
  return 1.f - 2.f / (e + 1.f);   // exact at +-inf, ~1e-6 abs err
}

// Truncation hi/lo bf16 split of a float pair, packed k-ascending (even in low half).
// hi = top 16 bits (exact bf16 by truncation); lo = bf16_trunc(v - hi); residual ~2^-16 rel.
__device__ __forceinline__ void split2(float va, float vb, unsigned& hi, unsigned& lo) {
  const unsigned ua = __float_as_uint(va), ub = __float_as_uint(vb);
  const unsigned ha = ua & 0xFFFF0000u, hb = ub & 0xFFFF0000u;
  hi = (ha >> 16) | hb;
  const unsigned la = __float_as_uint(va - __uint_as_float(ha));
  const unsigned lb = __float_as_uint(vb - __uint_as_float(hb));
  lo = (la >> 16) | (lb & 0xFFFF0000u);
}

// ---------- Kernel 0: one-time W1 -> transposed bf16 hi/lo split (Wt[col][k]) ----------
__global__ __launch_bounds__(256) void k_prepw(
    const float* __restrict__ W1, ushort* __restrict__ Wt_hi, ushort* __restrict__ Wt_lo) {
  const int i = blockIdx.x * 256 + threadIdx.x;   // < 4096
  const int col = i >> 6, k = i & 63;
  const float v = W1[k * HID + col];
  const unsigned u = __float_as_uint(v);
  const unsigned h = u & 0xFFFF0000u;
  Wt_hi[i] = (ushort)(h >> 16);
  const float lo = v - __uint_as_float(h);
  Wt_lo[i] = (ushort)(__float_as_uint(lo) >> 16);
}

// ---------- Kernel 1: saliency via bf16x3 MFMA, zero LDS ----------
// Block: 256 thr (4 waves); wave handles 32 rows; block 128 rows.
// A fragments: x[row][k0..k0+8] direct from global (32 contiguous bytes), split in-register.
// B fragments: preconverted Wt_hi/lo[col][k], 16B loads, L1-resident.
__global__ __launch_bounds__(256) void k_saliency(
    const float* __restrict__ x, const ushort* __restrict__ Wt_hi,
    const ushort* __restrict__ Wt_lo, const float* __restrict__ b1,
    const float* __restrict__ w_s, float* __restrict__ sal) {
  const int t = threadIdx.x;
  const int lane = t & 63, wid = t >> 6;
  const int r16 = lane & 15, kq = lane >> 4;      // A-row / B-col lane, k-quad
  const int rowbase = blockIdx.x * 128 + wid * 32;

  union U8 { bf16x8 v; unsigned u[4]; };

  // B fragments: col = ct*16 + r16, k0 = kc*32 + kq*8
  bf16x8 bHi[4][2], bLo[4][2];
#pragma unroll
  for (int ct = 0; ct < 4; ++ct)
#pragma unroll
    for (int kc = 0; kc < 2; ++kc) {
      const int off = (ct * 16 + r16) * 64 + kc * 32 + kq * 8;
      bHi[ct][kc] = *(const bf16x8*)(Wt_hi + off);
      bLo[ct][kc] = *(const bf16x8*)(Wt_lo + off);
    }

  f32x4 acc[2][4];
#pragma unroll
  for (int rt = 0; rt < 2; ++rt)
#pragma unroll
    for (int ct = 0; ct < 4; ++ct) acc[rt][ct] = (f32x4)0.f;

#pragma unroll
  for (int rt = 0; rt < 2; ++rt) {
    const float* __restrict__ xr = x + ((size_t)(rowbase + rt * 16 + r16)) * DIM;
#pragma unroll
    for (int kc = 0; kc < 2; ++kc) {
      const float4 a0 = *(const float4*)(xr + kc * 32 + kq * 8);
      const float4 a1 = *(const float4*)(xr + kc * 32 + kq * 8 + 4);
      U8 ahi, alo;
      split2(a0.x, a0.y, ahi.u[0], alo.u[0]);
      split2(a0.z, a0.w, ahi.u[1], alo.u[1]);
      split2(a1.x, a1.y, ahi.u[2], alo.u[2]);
      split2(a1.z, a1.w, ahi.u[3], alo.u[3]);
#pragma unroll
      for (int ct = 0; ct < 4; ++ct) {
        acc[rt][ct] = __builtin_amdgcn_mfma_f32_16x16x32_bf16(ahi.v, bHi[ct][kc], acc[rt][ct], 0, 0, 0);
        acc[rt][ct] = __builtin_amdgcn_mfma_f32_16x16x32_bf16(alo.v, bHi[ct][kc], acc[rt][ct], 0, 0, 0);
        acc[rt][ct] = __builtin_amdgcn_mfma_f32_16x16x32_bf16(ahi.v, bLo[ct][kc], acc[rt][ct], 0, 0, 0);
      }
    }
  }

  // epilogue: s_row = sum_hid w_s[h]*tanh(acc+b1[h]); C layout: col=lane&15, row=(lane>>4)*4+reg
  float ws4[4], b14[4];
#pragma unroll
  for (int ct = 0; ct < 4; ++ct) { ws4[ct] = w_s[ct * 16 + r16]; b14[ct] = b1[ct * 16 + r16]; }
#pragma unroll
  for (int rt = 0; rt < 2; ++rt) {
    float s[4] = {0.f, 0.f, 0.f, 0.f};
#pragma unroll
    for (int ct = 0; ct < 4; ++ct)
#pragma unroll
      for (int r = 0; r < 4; ++r)
        s[r] = fmaf(ws4[ct], fast_tanh(acc[rt][ct][r] + b14[ct]), s[r]);
#pragma unroll
    for (int r = 0; r < 4; ++r) {
#pragma unroll
      for (int off = 1; off < 16; off <<= 1) s[r] += __shfl_xor(s[r], off);
    }
    if (r16 == 0) {
#pragma unroll
      for (int r = 0; r < 4; ++r) {
        const int grow = rowbase + rt * 16 + kq * 4 + r;
        const float sv = s[r];
        sal[grow] = fmaxf(sv, 0.f) + log1pf(__expf(-fabsf(sv)));   // softplus
      }
    }
  }
}

// ---------- Kernel 2: per-chunk (2048 elems) online-softmax partials + top-16 ----------
// Indices stored WITHIN-ROW (0..N-1): chunk c covers row (c>>3), row-offset (c&7)*2048.
__global__ __launch_bounds__(256) void k_chunk(
    const float* __restrict__ sal, float* __restrict__ cmax, float* __restrict__ csum,
    float* __restrict__ cval, int* __restrict__ cidx) {
  __shared__ float sb[4], ss[4], wv[4];
  __shared__ int wi[4];
  const int t = threadIdx.x, c = blockIdx.x;
  const int rowoff = (c & 7) * 2048;          // within-row offset of this chunk
  const size_t gbase = (size_t)c * 2048;      // flat offset into sal
  float v[8];
#pragma unroll
  for (int j = 0; j < 8; ++j) v[j] = sal[gbase + t + 256 * j];

  float m = v[0];
#pragma unroll
  for (int j = 1; j < 8; ++j) m = fmaxf(m, v[j]);
#pragma unroll
  for (int off = 1; off < 64; off <<= 1) m = fmaxf(m, __shfl_xor(m, off));
  if ((t & 63) == 0) sb[t >> 6] = m;
  __syncthreads();
  m = fmaxf(fmaxf(sb[0], sb[1]), fmaxf(sb[2], sb[3]));

  float se = 0.f;
#pragma unroll
  for (int j = 0; j < 8; ++j) se += __expf(v[j] - m);
#pragma unroll
  for (int off = 1; off < 64; off <<= 1) se += __shfl_xor(se, off);
  if ((t & 63) == 0) ss[t >> 6] = se;
  __syncthreads();
  if (t == 0) { cmax[c] = m; csum[c] = ss[0] + ss[1] + ss[2] + ss[3]; }

  // top-16 of chunk, (value desc, index asc), indices within-row
  for (int k = 0; k < MP; ++k) {
    float bv = v[0]; int bj = 0;
#pragma unroll
    for (int j = 1; j < 8; ++j)
      if (v[j] > bv) { bv = v[j]; bj = j; }      // strict >: keeps smallest idx in-thread
    int bi = rowoff + t + 256 * bj;
#pragma unroll
    for (int off = 1; off < 64; off <<= 1) {
      const float ov = __shfl_xor(bv, off);
      const int   oi = __shfl_xor(bi, off);
      if (ov > bv || (ov == bv && oi < bi)) { bv = ov; bi = oi; }
    }
    if ((t & 63) == 0) { wv[t >> 6] = bv; wi[t >> 6] = bi; }
    __syncthreads();
    float Bv = wv[0]; int Bi = wi[0];
#pragma unroll
    for (int w = 1; w < 4; ++w)
      if (wv[w] > Bv || (wv[w] == Bv && wi[w] < Bi)) { Bv = wv[w]; Bi = wi[w]; }
    if (t == 0) { cval[c * MP + k] = Bv; cidx[c * MP + k] = Bi; }
    // deflate winner (static indexing — no scratch)
    const int relidx = Bi - rowoff;
#pragma unroll
    for (int jj = 0; jj < 8; ++jj)
      if (relidx == t + 256 * jj) v[jj] = -INFINITY;
    __syncthreads();
  }
}

// ---------- Kernel 3: merge 8 chunks per row -> row stats + global top-16 ----------
__global__ __launch_bounds__(256) void k_merge(
    const float* __restrict__ cmax, const float* __restrict__ csum,
    const float* __restrict__ cval, const int* __restrict__ cidx,
    float* __restrict__ rowmax, float* __restrict__ rowinv,
    int* __restrict__ top_idx, float* __restrict__ top_sal) {
  __shared__ float wv[4];
  __shared__ int wi[4];
  const int b = blockIdx.x, t = threadIdx.x;
  if (t == 0) {
    float mx = cmax[b * 8];
#pragma unroll
    for (int c = 1; c < 8; ++c) mx = fmaxf(mx, cmax[b * 8 + c]);
    float S = 0.f;
#pragma unroll
    for (int c = 0; c < 8; ++c) S += csum[b * 8 + c] * __expf(cmax[b * 8 + c] - mx);
    rowmax[b] = mx; rowinv[b] = 1.f / S;
  }
  float v = -INFINITY; int i = 0x7fffffff;
  if (t < 128) { v = cval[b * 128 + t]; i = cidx[b * 128 + t]; }
  for (int k = 0; k < MP; ++k) {
    float bv = v; int bi = i;
#pragma unroll
    for (int off = 1; off < 64; off <<= 1) {
      const float ov = __shfl_xor(bv, off);
      const int   oi = __shfl_xor(bi, off);
      if (ov > bv || (ov == bv && oi < bi)) { bv = ov; bi = oi; }
    }
    if ((t & 63) == 0) { wv[t >> 6] = bv; wi[t >> 6] = bi; }
    __syncthreads();
    float Bv = wv[0]; int Bi = wi[0];
#pragma unroll
    for (int w = 1; w < 4; ++w)
      if (wv[w] > Bv || (wv[w] == Bv && wi[w] < Bi)) { Bv = wv[w]; Bi = wi[w]; }
    if (t == 0) { top_idx[b * MP + k] = Bi; top_sal[b * MP + k] = Bv; }
    if (i == Bi) v = -INFINITY;
    __syncthreads();
  }
}

// ---------- Kernel 4: y_star elementwise ----------
__global__ __launch_bounds__(256) void k_ystar(
    float* __restrict__ y, const float* __restrict__ rowmax, const float* __restrict__ rowinv) {
  const int gi = blockIdx.x * 256 + threadIdx.x;
  const int b = gi >> 14;                       // N = 16384
  const float mx = rowmax[b], inv = rowinv[b];
  const float v = y[gi];
  const float sig = 1.f / (1.f + __expf(-v));
  y[gi] = fmaf(0.5f, sig, 4.f * __expf(v - mx) * inv);
}

// ---------- Kernel 5: gather + lift (66->16) + project (16->512) ----------
__global__ __launch_bounds__(256) void k_tokens(
    const float* __restrict__ x,
    const int* __restrict__ top_idx, const float* __restrict__ top_sal,
    const float* __restrict__ W_lift, const float* __restrict__ b_lift,
    const float* __restrict__ W_proj, const float* __restrict__ b_proj,
    const float* __restrict__ mu, const float* __restrict__ sigma,
    float* __restrict__ tokens) {
  __shared__ float part[16][17];
  __shared__ float lifted[KD];
  const int bk = blockIdx.x, b = bk >> 4, t = threadIdx.x;
  const int kd = t & 15, seg = t >> 4;
  const int idx = top_idx[bk];                  // within-row index (0..N-1)
  const float salv = top_sal[bk];
  const float* __restrict__ xr = x + ((size_t)b * N + idx) * DIM;

  float p = 0.f;
#pragma unroll
  for (int u = 0; u < 4; ++u) {
    const int a = seg * 4 + u;
    p = fmaf((xr[a] - mu[a]) / sigma[a], W_lift[a * KD + kd], p);
  }
  if (seg == 0) p = fmaf((salv - mu[64]) / sigma[64], W_lift[64 * KD + kd], p);
  if (seg == 1) {
    const float pos = (float)idx / (float)N;
    p = fmaf((pos - mu[65]) / sigma[65], W_lift[65 * KD + kd], p);
  }
  part[seg][kd] = p;
  __syncthreads();
  if (t < KD) {
    float s = b_lift[t];
#pragma unroll
    for (int g = 0; g < 16; ++g) s += part[g][t];
    lifted[t] = s;
  }
  __syncthreads();

  const float2* __restrict__ Wp2 = (const float2*)W_proj;
  float2 a2 = ((const float2*)b_proj)[t];
#pragma unroll
  for (int c = 0; c < KD; ++c) {
    const float2 w = Wp2[c * 256 + t];
    a2.x = fmaf(lifted[c], w.x, a2.x);
    a2.y = fmaf(lifted[c], w.y, a2.y);
  }
  ((float2*)(tokens + (size_t)bk * DM))[t] = a2;
}

extern "C" void kernel_launch(void* const* d_in, const int* in_sizes, int n_in,
                              void* d_out, int out_size, void* d_ws, size_t ws_size,
                              hipStream_t stream) {
  const float* x      = (const float*)d_in[0];
  const float* W1     = (const float*)d_in[1];
  const float* b1     = (const float*)d_in[2];
  // d_in[3] = w_e (unused by the reference outputs)
  const float* w_s    = (const float*)d_in[4];
  const float* W_lift = (const float*)d_in[5];
  const float* b_lift = (const float*)d_in[6];
  const float* W_proj = (const float*)d_in[7];
  const float* b_proj = (const float*)d_in[8];
  const float* mu     = (const float*)d_in[9];
  const float* sigma  = (const float*)d_in[10];

  float* tokens = (float*)d_out;                       // [B, MP, DM]
  float* ystar  = (float*)d_out + (size_t)B * MP * DM; // [B, N] (saliency staged here)

  // workspace layout (floats)
  int*   top_idx = (int*)d_ws;                 // 512
  float* top_sal = (float*)d_ws + 512;         // 512
  float* cmax    = (float*)d_ws + 1024;        // 256
  float* csum    = (float*)d_ws + 1280;        // 256
  float* rowmax  = (float*)d_ws + 1536;        // 32
  float* rowinv  = (float*)d_ws + 1568;        // 32
  float* cval    = (float*)d_ws + 1600;        // 4096
  int*   cidx    = (int*)d_ws + 5696;          // 4096 -> ends at float 9792
  ushort* Wt_hi  = (ushort*)((float*)d_ws + 9792);   // 4096 ushorts (8 KB)
  ushort* Wt_lo  = Wt_hi + 4096;                     // 4096 ushorts (8 KB)

  k_prepw<<<16, 256, 0, stream>>>(W1, Wt_hi, Wt_lo);
  k_saliency<<<(B * N) / 128, 256, 0, stream>>>(x, Wt_hi, Wt_lo, b1, w_s, ystar);
  k_chunk<<<(B * N) / 2048, 256, 0, stream>>>(ystar, cmax, csum, cval, cidx);
  k_merge<<<B, 256, 0, stream>>>(cmax, csum, cval, cidx, rowmax, rowinv, top_idx, top_sal);
  k_ystar<<<(B * N) / 256, 256, 0, stream>>>(ystar, rowmax, rowinv);
  k_tokens<<<B * MP, 256, 0, stream>>>(x, top_idx, top_sal, W_lift, b_lift,
                                       W_proj, b_proj, mu, sigma, tokens);
}